// Round 1
// baseline (2128.328 us; speedup 1.0000x reference)
//
#include <hip/hip_runtime.h>
#include <hip/hip_bf16.h>

constexpr int BS = 64;    // batch
constexpr int CH = 256;   // channels
constexpr int KB = 64;    // bases (K)
constexpr int NP = 4096;  // pixels (H*W)
constexpr int NSPLIT = 4; // z-step reduction split

// ---------------------------------------------------------------------------
// Generic NN GEMM: C[b][m][n] = sum_k A[b][m][k] * B[b][k][n]  (row-major)
// EPI: 0 plain, 1 +bias (conv1), 2 store + rowwise sum-of-squares atomics
//      (mu-step), 3 relu store (xr), 4 store + row sum & sumsq atomics (conv2)
// ---------------------------------------------------------------------------
template<int MT, int NT, int KC, int TM, int TN, int EPI>
__global__ __launch_bounds__(256)
void gemm_nn(const float* __restrict__ A, long Asb,
             const float* __restrict__ Bm, long Bsb,
             float* __restrict__ Cm, long Csb,
             const float* __restrict__ bias,
             float* __restrict__ red,
             int M, int Nc, int Kr)
{
  constexpr int NTH_N = NT / TN;
  constexpr int NTH_M = MT / TM;
  static_assert(NTH_M * NTH_N == 256, "thread grid must be 256");
  constexpr int LA = MT * KC / (4 * 256);
  constexpr int LB = NT * KC / (4 * 256);

  __shared__ float la[KC][MT + 4];   // A tile transposed [k][m], +4 pad
  __shared__ float lb[KC][NT];       // B tile natural   [k][n]

  const int tid = threadIdx.x;
  const int b = blockIdx.z;
  const int m0 = blockIdx.y * MT;
  const int n0 = blockIdx.x * NT;
  const int tmi = tid / NTH_N;
  const int tni = tid % NTH_N;

  const float* Ab = A + (long)b * Asb;
  const float* Bb = Bm + (long)b * Bsb;

  float acc[TM][TN];
  #pragma unroll
  for (int i = 0; i < TM; ++i)
    #pragma unroll
    for (int j = 0; j < TN; ++j) acc[i][j] = 0.f;

  for (int k0 = 0; k0 < Kr; k0 += KC) {
    __syncthreads();
    #pragma unroll
    for (int i = 0; i < LA; ++i) {
      int slot = tid + i * 256;
      int m  = slot / (KC / 4);
      int kq = slot % (KC / 4);
      const float4 v = *(const float4*)(Ab + (long)(m0 + m) * Kr + k0 + kq * 4);
      la[kq * 4 + 0][m] = v.x;
      la[kq * 4 + 1][m] = v.y;
      la[kq * 4 + 2][m] = v.z;
      la[kq * 4 + 3][m] = v.w;
    }
    #pragma unroll
    for (int i = 0; i < LB; ++i) {
      int slot = tid + i * 256;
      int kk = slot / (NT / 4);
      int nq = slot % (NT / 4);
      *(float4*)(&lb[kk][nq * 4]) =
          *(const float4*)(Bb + (long)(k0 + kk) * Nc + n0 + nq * 4);
    }
    __syncthreads();
    #pragma unroll
    for (int kk = 0; kk < KC; ++kk) {
      float ar[TM], br[TN];
      #pragma unroll
      for (int i = 0; i < TM; i += 4)
        *(float4*)(ar + i) = *(const float4*)(&la[kk][tmi * TM + i]);
      #pragma unroll
      for (int j = 0; j < TN; j += 4)
        *(float4*)(br + j) = *(const float4*)(&lb[kk][tni * TN + j]);
      #pragma unroll
      for (int i = 0; i < TM; ++i)
        #pragma unroll
        for (int j = 0; j < TN; ++j)
          acc[i][j] = fmaf(ar[i], br[j], acc[i][j]);
    }
  }

  float* Cb = Cm + (long)b * Csb;
  #pragma unroll
  for (int i = 0; i < TM; ++i) {
    const int m = m0 + tmi * TM + i;
    float* crow = Cb + (long)m * Nc + n0 + tni * TN;
    float bv = 0.f;
    if constexpr (EPI == 1) bv = bias[m];
    float vals[TN];
    #pragma unroll
    for (int j = 0; j < TN; ++j) {
      float val = acc[i][j] + bv;
      if constexpr (EPI == 3) val = fmaxf(val, 0.f);
      vals[j] = val;
    }
    #pragma unroll
    for (int j = 0; j < TN; j += 4)
      *(float4*)(crow + j) = *(const float4*)(vals + j);

    if constexpr (EPI == 2) {
      float ssl = 0.f;
      #pragma unroll
      for (int j = 0; j < TN; ++j) ssl += acc[i][j] * acc[i][j];
      #pragma unroll
      for (int o = 8; o >= 1; o >>= 1) ssl += __shfl_down(ssl, o, 16);
      if (tni == 0) atomicAdd(&red[b * M + m], ssl);
    }
    if constexpr (EPI == 4) {
      float s1 = 0.f, s2 = 0.f;
      #pragma unroll
      for (int j = 0; j < TN; ++j) { s1 += acc[i][j]; s2 += acc[i][j] * acc[i][j]; }
      #pragma unroll
      for (int o = 8; o >= 1; o >>= 1) {
        s1 += __shfl_down(s1, o, 16);
        s2 += __shfl_down(s2, o, 16);
      }
      if (tni == 0) {
        atomicAdd(&red[(b * M + m) * 2 + 0], s1);
        atomicAdd(&red[(b * M + m) * 2 + 1], s2);
      }
    }
  }
}

// ---------------------------------------------------------------------------
// z-step (NT GEMM): Zp[sp][b][k][c] = sum_{n in split sp} mu[b][k][n]*xf[b][c][n]
// mu rows are scaled on load by 1/(1e-6+sqrt(ssq[b][k])) (fused l2norm).
// ---------------------------------------------------------------------------
__global__ __launch_bounds__(256)
void zstep(const float* __restrict__ MU, long MUsb, const float* __restrict__ ssq,
           const float* __restrict__ XF, float* __restrict__ Zp)
{
  constexpr int NC = 64;
  __shared__ float lmu[NC][KB + 4];   // [n][k]
  __shared__ float lxf[NC][64 + 4];   // [n][c]

  const int tid = threadIdx.x;
  const int b = blockIdx.z, sp = blockIdx.y, ct = blockIdx.x;
  const int tk = tid / 16, tc = tid % 16;

  const float* MUb = MU + (long)b * MUsb;
  const float* XFb = XF + ((long)b * CH + ct * 64) * NP;

  // per-slot mu row scale (k fixed per slot across chunks)
  float rs[4];
  #pragma unroll
  for (int i = 0; i < 4; ++i) {
    int k = (tid + i * 256) / 16;
    rs[i] = ssq ? 1.f / (1e-6f + sqrtf(ssq[b * KB + k])) : 1.f;
  }

  float acc[4][4];
  #pragma unroll
  for (int i = 0; i < 4; ++i)
    #pragma unroll
    for (int j = 0; j < 4; ++j) acc[i][j] = 0.f;

  const int nbeg = sp * (NP / NSPLIT);
  const int nend = nbeg + (NP / NSPLIT);
  for (int n0 = nbeg; n0 < nend; n0 += NC) {
    __syncthreads();
    #pragma unroll
    for (int i = 0; i < 4; ++i) {
      int slot = tid + i * 256;
      int k = slot / 16, nq = slot % 16;
      const float4 v = *(const float4*)(MUb + (long)k * NP + n0 + nq * 4);
      lmu[nq * 4 + 0][k] = v.x * rs[i];
      lmu[nq * 4 + 1][k] = v.y * rs[i];
      lmu[nq * 4 + 2][k] = v.z * rs[i];
      lmu[nq * 4 + 3][k] = v.w * rs[i];
    }
    #pragma unroll
    for (int i = 0; i < 4; ++i) {
      int slot = tid + i * 256;
      int c = slot / 16, nq = slot % 16;
      const float4 v = *(const float4*)(XFb + (long)c * NP + n0 + nq * 4);
      lxf[nq * 4 + 0][c] = v.x;
      lxf[nq * 4 + 1][c] = v.y;
      lxf[nq * 4 + 2][c] = v.z;
      lxf[nq * 4 + 3][c] = v.w;
    }
    __syncthreads();
    #pragma unroll
    for (int kk = 0; kk < NC; ++kk) {
      float a[4], c4[4];
      *(float4*)a  = *(const float4*)(&lmu[kk][tk * 4]);
      *(float4*)c4 = *(const float4*)(&lxf[kk][tc * 4]);
      #pragma unroll
      for (int i = 0; i < 4; ++i)
        #pragma unroll
        for (int j = 0; j < 4; ++j)
          acc[i][j] = fmaf(a[i], c4[j], acc[i][j]);
    }
  }

  #pragma unroll
  for (int i = 0; i < 4; ++i) {
    int k = tk * 4 + i;
    float4 v = { acc[i][0], acc[i][1], acc[i][2], acc[i][3] };
    *(float4*)(Zp + (((long)sp * BS + b) * KB + k) * CH + ct * 64 + tc * 4) = v;
  }
}

// ---------------------------------------------------------------------------
// softmax over K (axis=1) per (b,c) + channel normalization over C per (b,k).
// One block per b; thread t owns column c=t; all K=64 values in registers.
// Writes zn[b][k][c] (= softmax / channel-sum) and, if writeT, zsmT[b][c][k]
// (= raw softmax, transposed — the A operand of the xr GEMM).
// ---------------------------------------------------------------------------
__global__ __launch_bounds__(256)
void em_softmax(const float* __restrict__ Zp, float* __restrict__ zn,
                float* __restrict__ zsmT, int writeT)
{
  __shared__ float wsum[4 * KB];
  __shared__ float rsc[KB];

  const int b = blockIdx.x;
  const int t = threadIdx.x;        // channel index c
  const int lane = t & 63, w = t >> 6;
  constexpr long SPOFF = (long)BS * KB * CH;

  float z[KB];
  #pragma unroll
  for (int k = 0; k < KB; ++k) {
    long base = ((long)b * KB + k) * CH + t;
    z[k] = Zp[base] + Zp[SPOFF + base] + Zp[2 * SPOFF + base] + Zp[3 * SPOFF + base];
  }
  float m = z[0];
  #pragma unroll
  for (int k = 1; k < KB; ++k) m = fmaxf(m, z[k]);
  float s = 0.f;
  #pragma unroll
  for (int k = 0; k < KB; ++k) { z[k] = expf(z[k] - m); s += z[k]; }
  float inv = 1.f / s;
  #pragma unroll
  for (int k = 0; k < KB; ++k) z[k] *= inv;   // z[k] = softmax over bases

  // channel sums per k (reduce over the 256 c's)
  #pragma unroll
  for (int k = 0; k < KB; ++k) {
    float v = z[k];
    #pragma unroll
    for (int o = 32; o >= 1; o >>= 1) v += __shfl_xor(v, o);
    if (lane == 0) wsum[w * KB + k] = v;
  }
  __syncthreads();
  if (t < KB) {
    float v = wsum[t] + wsum[KB + t] + wsum[2 * KB + t] + wsum[3 * KB + t];
    rsc[t] = 1.f / (1e-6f + v);
  }
  __syncthreads();

  #pragma unroll
  for (int k = 0; k < KB; ++k)
    zn[((long)b * KB + k) * CH + t] = z[k] * rsc[k];

  if (writeT) {
    #pragma unroll
    for (int k = 0; k < KB; k += 4) {
      float4 v = { z[k], z[k + 1], z[k + 2], z[k + 3] };
      *(float4*)(zsmT + ((long)b * CH + t) * KB + k) = v;
    }
  }
}

// mu_s[b][k][n] = mu_raw[b][k][n] * scale_weight[b][k] / (1e-6+sqrt(ssq[b][k]))
__global__ void finalize_mu(const float* __restrict__ mu_raw,
                            const float* __restrict__ ssq,
                            const float* __restrict__ sw,
                            float* __restrict__ mu_s)
{
  long i4 = (long)blockIdx.x * blockDim.x + threadIdx.x;
  constexpr long TOT = (long)BS * KB * NP / 4;
  if (i4 >= TOT) return;
  int bk = (int)(i4 / (NP / 4));
  float sc = sw[bk] / (1e-6f + sqrtf(ssq[bk]));
  float4 v = ((const float4*)mu_raw)[i4];
  v.x *= sc; v.y *= sc; v.z *= sc; v.w *= sc;
  ((float4*)mu_s)[i4] = v;
}

// out = relu((x2 - mean)/sqrt(var+1e-5) + x), in place over the x2 staging.
__global__ void instnorm(float* __restrict__ out, const float* __restrict__ x,
                         const float* __restrict__ sums)
{
  long i4 = (long)blockIdx.x * blockDim.x + threadIdx.x;
  constexpr long TOT = (long)BS * CH * NP / 4;
  if (i4 >= TOT) return;
  int bc = (int)(i4 / (NP / 4));
  float mean = sums[bc * 2 + 0] * (1.f / NP);
  float var  = sums[bc * 2 + 1] * (1.f / NP) - mean * mean;
  float is = rsqrtf(var + 1e-5f);
  float4 v = ((const float4*)out)[i4];
  float4 xv = ((const float4*)x)[i4];
  v.x = fmaxf((v.x - mean) * is + xv.x, 0.f);
  v.y = fmaxf((v.y - mean) * is + xv.y, 0.f);
  v.z = fmaxf((v.z - mean) * is + xv.z, 0.f);
  v.w = fmaxf((v.w - mean) * is + xv.w, 0.f);
  ((float4*)out)[i4] = v;
}

extern "C" void kernel_launch(void* const* d_in, const int* in_sizes, int n_in,
                              void* d_out, int out_size, void* d_ws, size_t ws_size,
                              hipStream_t stream)
{
  const float* x   = (const float*)d_in[0];
  const float* sw  = (const float*)d_in[1];
  const float* w1  = (const float*)d_in[2];
  const float* b1  = (const float*)d_in[3];
  const float* w2  = (const float*)d_in[4];
  const float* mu0 = (const float*)d_in[5];

  float* out  = (float*)d_out;                    // B*C*N  (x2 staging, then out)
  float* mu_s = out + (long)BS * CH * NP;         // B*K*N

  float* ws     = (float*)d_ws;
  float* xf     = ws;                             // B*C*N   (reused as xr)
  float* mu_raw = xf + (long)BS * CH * NP;        // B*K*N
  float* zp     = mu_raw + (long)BS * KB * NP;    // NSPLIT*B*K*C
  float* zn     = zp + (long)NSPLIT * BS * KB * CH; // B*K*C
  float* zsmT   = zn + (long)BS * KB * CH;        // B*C*K
  float* ss     = zsmT + (long)BS * CH * KB;      // 3 * B*K
  float* isums  = ss + 3 * BS * KB;               // B*C*2

  // zero the atomic accumulators (ss[3 regions] + isums are contiguous)
  hipMemsetAsync(ss, 0, (size_t)(3 * BS * KB + 2 * BS * CH) * sizeof(float), stream);

  dim3 thr(256);

  // conv1: xf = W1 @ x + b1
  gemm_nn<128, 128, 32, 8, 8, 1><<<dim3(NP / 128, CH / 128, BS), thr, 0, stream>>>(
      w1, 0, x, (long)CH * NP, xf, (long)CH * NP, b1, nullptr, CH, NP, CH);

  const float* mu_in = mu0;
  long mu_sb = 0;
  const float* ssq = nullptr;
  for (int st = 0; st < 3; ++st) {
    zstep<<<dim3(CH / 64, NSPLIT, BS), thr, 0, stream>>>(mu_in, mu_sb, ssq, xf, zp);
    em_softmax<<<dim3(BS), thr, 0, stream>>>(zp, zn, zsmT, st == 2 ? 1 : 0);
    gemm_nn<64, 128, 32, 4, 8, 2><<<dim3(NP / 128, 1, BS), thr, 0, stream>>>(
        zn, (long)KB * CH, xf, (long)CH * NP, mu_raw, (long)KB * NP,
        nullptr, ss + st * BS * KB, KB, NP, CH);
    mu_in = mu_raw; mu_sb = (long)KB * NP; ssq = ss + st * BS * KB;
  }

  finalize_mu<<<dim3((BS * KB * NP / 4 + 255) / 256), thr, 0, stream>>>(
      mu_raw, ss + 2 * BS * KB, sw, mu_s);

  // xr = relu(z^T @ mu_s), into xf's buffer
  gemm_nn<128, 128, 32, 8, 8, 3><<<dim3(NP / 128, CH / 128, BS), thr, 0, stream>>>(
      zsmT, (long)CH * KB, mu_s, (long)KB * NP, xf, (long)CH * NP,
      nullptr, nullptr, CH, NP, KB);

  // conv2: x2 = W2 @ xr (staged into d_out) + per-(b,c) sum/sumsq
  gemm_nn<128, 128, 32, 8, 8, 4><<<dim3(NP / 128, CH / 128, BS), thr, 0, stream>>>(
      w2, 0, xf, (long)CH * NP, out, (long)CH * NP, nullptr, isums, CH, NP, CH);

  instnorm<<<dim3(BS * CH * NP / 4 / 256), thr, 0, stream>>>(out, x, isums);
}

// Round 3
// 1949.014 us; speedup vs baseline: 1.0920x; 1.0920x over previous
//
#include <hip/hip_runtime.h>
#include <hip/hip_bf16.h>

typedef __bf16 bf16x8 __attribute__((ext_vector_type(8)));
typedef float  f32x4  __attribute__((ext_vector_type(4)));
typedef unsigned short u16;

constexpr int BS = 64;    // batch
constexpr int CH = 256;   // channels
constexpr int KB = 64;    // bases
constexpr int NP = 4096;  // pixels
constexpr int NSPLIT = 4; // z-step reduction split

__device__ inline u16 f2b(float f) {
  __hip_bfloat16 h = __float2bfloat16(f);
  return __builtin_bit_cast(u16, h);
}

// ---------------------------------------------------------------------------
// fp32 NN GEMM (round-1, proven): C[b][m][n] = sum_k A[b][m][k] * B[b][k][n]
// EPI: 1 +bias (conv1), 2 store + rowwise sum-of-squares atomics (mu-step)
// ---------------------------------------------------------------------------
template<int MT, int NT, int KC, int TM, int TN, int EPI>
__global__ __launch_bounds__(256)
void gemm_nn(const float* __restrict__ A, long Asb,
             const float* __restrict__ Bm, long Bsb,
             float* __restrict__ Cm, long Csb,
             const float* __restrict__ bias,
             float* __restrict__ red,
             int M, int Nc, int Kr)
{
  constexpr int NTH_N = NT / TN;
  constexpr int NTH_M = MT / TM;
  static_assert(NTH_M * NTH_N == 256, "thread grid must be 256");
  constexpr int LA = MT * KC / (4 * 256);
  constexpr int LB = NT * KC / (4 * 256);

  __shared__ float la[KC][MT + 4];
  __shared__ float lb[KC][NT];

  const int tid = threadIdx.x;
  const int b = blockIdx.z;
  const int m0 = blockIdx.y * MT;
  const int n0 = blockIdx.x * NT;
  const int tmi = tid / NTH_N;
  const int tni = tid % NTH_N;

  const float* Ab = A + (long)b * Asb;
  const float* Bb = Bm + (long)b * Bsb;

  float acc[TM][TN];
  #pragma unroll
  for (int i = 0; i < TM; ++i)
    #pragma unroll
    for (int j = 0; j < TN; ++j) acc[i][j] = 0.f;

  for (int k0 = 0; k0 < Kr; k0 += KC) {
    __syncthreads();
    #pragma unroll
    for (int i = 0; i < LA; ++i) {
      int slot = tid + i * 256;
      int m  = slot / (KC / 4);
      int kq = slot % (KC / 4);
      const float4 v = *(const float4*)(Ab + (long)(m0 + m) * Kr + k0 + kq * 4);
      la[kq * 4 + 0][m] = v.x;
      la[kq * 4 + 1][m] = v.y;
      la[kq * 4 + 2][m] = v.z;
      la[kq * 4 + 3][m] = v.w;
    }
    #pragma unroll
    for (int i = 0; i < LB; ++i) {
      int slot = tid + i * 256;
      int kk = slot / (NT / 4);
      int nq = slot % (NT / 4);
      *(float4*)(&lb[kk][nq * 4]) =
          *(const float4*)(Bb + (long)(k0 + kk) * Nc + n0 + nq * 4);
    }
    __syncthreads();
    #pragma unroll
    for (int kk = 0; kk < KC; ++kk) {
      float ar[TM], br[TN];
      #pragma unroll
      for (int i = 0; i < TM; i += 4)
        *(float4*)(ar + i) = *(const float4*)(&la[kk][tmi * TM + i]);
      #pragma unroll
      for (int j = 0; j < TN; j += 4)
        *(float4*)(br + j) = *(const float4*)(&lb[kk][tni * TN + j]);
      #pragma unroll
      for (int i = 0; i < TM; ++i)
        #pragma unroll
        for (int j = 0; j < TN; ++j)
          acc[i][j] = fmaf(ar[i], br[j], acc[i][j]);
    }
  }

  float* Cb = Cm + (long)b * Csb;
  #pragma unroll
  for (int i = 0; i < TM; ++i) {
    const int m = m0 + tmi * TM + i;
    float* crow = Cb + (long)m * Nc + n0 + tni * TN;
    float bv = 0.f;
    if constexpr (EPI == 1) bv = bias[m];
    float vals[TN];
    #pragma unroll
    for (int j = 0; j < TN; ++j) vals[j] = acc[i][j] + bv;
    #pragma unroll
    for (int j = 0; j < TN; j += 4)
      *(float4*)(crow + j) = *(const float4*)(vals + j);

    if constexpr (EPI == 2) {
      float ssl = 0.f;
      #pragma unroll
      for (int j = 0; j < TN; ++j) ssl += acc[i][j] * acc[i][j];
      #pragma unroll
      for (int o = 8; o >= 1; o >>= 1) ssl += __shfl_down(ssl, o, 16);
      if (tni == 0) atomicAdd(&red[b * M + m], ssl);
    }
  }
}

// ---------------------------------------------------------------------------
// fp32 z-step (round-1, proven): Zp[sp][b][k][c] = sum_n mu[k][n]*xf[c][n],
// mu rows scaled on load by 1/(1e-6+sqrt(ssq[b][k])) (fused l2norm).
// ---------------------------------------------------------------------------
__global__ __launch_bounds__(256)
void zstep(const float* __restrict__ MU, long MUsb, const float* __restrict__ ssq,
           const float* __restrict__ XF, float* __restrict__ Zp)
{
  constexpr int NC = 64;
  __shared__ float lmu[NC][KB + 4];
  __shared__ float lxf[NC][64 + 4];

  const int tid = threadIdx.x;
  const int b = blockIdx.z, sp = blockIdx.y, ct = blockIdx.x;
  const int tk = tid / 16, tc = tid % 16;

  const float* MUb = MU + (long)b * MUsb;
  const float* XFb = XF + ((long)b * CH + ct * 64) * NP;

  float rs[4];
  #pragma unroll
  for (int i = 0; i < 4; ++i) {
    int k = (tid + i * 256) / 16;
    rs[i] = ssq ? 1.f / (1e-6f + sqrtf(ssq[b * KB + k])) : 1.f;
  }

  float acc[4][4];
  #pragma unroll
  for (int i = 0; i < 4; ++i)
    #pragma unroll
    for (int j = 0; j < 4; ++j) acc[i][j] = 0.f;

  const int nbeg = sp * (NP / NSPLIT);
  const int nend = nbeg + (NP / NSPLIT);
  for (int n0 = nbeg; n0 < nend; n0 += NC) {
    __syncthreads();
    #pragma unroll
    for (int i = 0; i < 4; ++i) {
      int slot = tid + i * 256;
      int k = slot / 16, nq = slot % 16;
      const float4 v = *(const float4*)(MUb + (long)k * NP + n0 + nq * 4);
      lmu[nq * 4 + 0][k] = v.x * rs[i];
      lmu[nq * 4 + 1][k] = v.y * rs[i];
      lmu[nq * 4 + 2][k] = v.z * rs[i];
      lmu[nq * 4 + 3][k] = v.w * rs[i];
    }
    #pragma unroll
    for (int i = 0; i < 4; ++i) {
      int slot = tid + i * 256;
      int c = slot / 16, nq = slot % 16;
      const float4 v = *(const float4*)(XFb + (long)c * NP + n0 + nq * 4);
      lxf[nq * 4 + 0][c] = v.x;
      lxf[nq * 4 + 1][c] = v.y;
      lxf[nq * 4 + 2][c] = v.z;
      lxf[nq * 4 + 3][c] = v.w;
    }
    __syncthreads();
    #pragma unroll
    for (int kk = 0; kk < NC; ++kk) {
      float a[4], c4[4];
      *(float4*)a  = *(const float4*)(&lmu[kk][tk * 4]);
      *(float4*)c4 = *(const float4*)(&lxf[kk][tc * 4]);
      #pragma unroll
      for (int i = 0; i < 4; ++i)
        #pragma unroll
        for (int j = 0; j < 4; ++j)
          acc[i][j] = fmaf(a[i], c4[j], acc[i][j]);
    }
  }

  #pragma unroll
  for (int i = 0; i < 4; ++i) {
    int k = tk * 4 + i;
    float4 v = { acc[i][0], acc[i][1], acc[i][2], acc[i][3] };
    *(float4*)(Zp + (((long)sp * BS + b) * KB + k) * CH + ct * 64 + tc * 4) = v;
  }
}

// ---------------------------------------------------------------------------
// softmax over K + channel normalize (round-1, fp32); zsmT now bf16 [c][k].
// ---------------------------------------------------------------------------
__global__ __launch_bounds__(256)
void em_softmax(const float* __restrict__ Zp, float* __restrict__ zn,
                u16* __restrict__ zsmT, int writeT)
{
  __shared__ float wsum[4 * KB];
  __shared__ float rsc[KB];

  const int b = blockIdx.x;
  const int t = threadIdx.x;
  const int lane = t & 63, w = t >> 6;
  constexpr long SPOFF = (long)BS * KB * CH;

  float z[KB];
  #pragma unroll
  for (int k = 0; k < KB; ++k) {
    long base = ((long)b * KB + k) * CH + t;
    z[k] = Zp[base] + Zp[SPOFF + base] + Zp[2 * SPOFF + base] + Zp[3 * SPOFF + base];
  }
  float m = z[0];
  #pragma unroll
  for (int k = 1; k < KB; ++k) m = fmaxf(m, z[k]);
  float s = 0.f;
  #pragma unroll
  for (int k = 0; k < KB; ++k) { z[k] = expf(z[k] - m); s += z[k]; }
  float inv = 1.f / s;
  #pragma unroll
  for (int k = 0; k < KB; ++k) z[k] *= inv;

  #pragma unroll
  for (int k = 0; k < KB; ++k) {
    float v = z[k];
    #pragma unroll
    for (int o = 32; o >= 1; o >>= 1) v += __shfl_xor(v, o);
    if (lane == 0) wsum[w * KB + k] = v;
  }
  __syncthreads();
  if (t < KB) {
    float v = wsum[t] + wsum[KB + t] + wsum[2 * KB + t] + wsum[3 * KB + t];
    rsc[t] = 1.f / (1e-6f + v);
  }
  __syncthreads();

  #pragma unroll
  for (int k = 0; k < KB; ++k)
    zn[((long)b * KB + k) * CH + t] = z[k] * rsc[k];

  if (writeT) {
    #pragma unroll
    for (int k = 0; k < KB; k += 4) {
      ushort4 o;
      o.x = f2b(z[k]); o.y = f2b(z[k + 1]); o.z = f2b(z[k + 2]); o.w = f2b(z[k + 3]);
      *(ushort4*)(zsmT + ((long)b * CH + t) * KB + k) = o;
    }
  }
}

// ---------------------------------------------------------------------------
// finalize: mu_s fp32 (output) + mu_sT bf16 [n][k]; sc = sw/(1e-6+||mu_raw||)
// ---------------------------------------------------------------------------
__global__ __launch_bounds__(256)
void finalize_mu_t(const float* __restrict__ mu_raw, const float* __restrict__ ssq,
                   const float* __restrict__ sw, float* __restrict__ mu_s,
                   u16* __restrict__ mu_sT)
{
  __shared__ u16 ldsT[64][72];
  const int tid = threadIdx.x;
  const int b = blockIdx.y, n0 = blockIdx.x * 64;

  #pragma unroll
  for (int i = 0; i < 4; ++i) {
    int slot = tid + i * 256;        // 1024 float4 slots = 64k x 64n
    int k = slot >> 4, nq = slot & 15;
    float sc = sw[b * KB + k] / (1e-6f + sqrtf(ssq[b * KB + k]));
    float4 v = *(const float4*)(mu_raw + ((size_t)b * KB + k) * NP + n0 + nq * 4);
    v.x *= sc; v.y *= sc; v.z *= sc; v.w *= sc;
    *(float4*)(mu_s + ((size_t)b * KB + k) * NP + n0 + nq * 4) = v;
    ldsT[nq * 4 + 0][k] = f2b(v.x);
    ldsT[nq * 4 + 1][k] = f2b(v.y);
    ldsT[nq * 4 + 2][k] = f2b(v.z);
    ldsT[nq * 4 + 3][k] = f2b(v.w);
  }
  __syncthreads();
  #pragma unroll
  for (int i = 0; i < 2; ++i) {
    int slot = tid + i * 256;
    int n = slot >> 3, kq = slot & 7;
    uint4 v = *(const uint4*)(&ldsT[n][kq * 8]);
    *(uint4*)(mu_sT + (size_t)b * NP * KB + (size_t)(n0 + n) * KB + kq * 8) = v;
  }
}

// ---------------------------------------------------------------------------
// bf16 MFMA NT GEMM (round-2): C[m][n] = sum_k A[m][k]*B[n][k], BK=64,
// XOR-swizzled LDS. EPI: 3 relu+bf16 store, 4 fp32 store + row sum/sumsq.
// ---------------------------------------------------------------------------
template<int BM, int BN, int WR, int WC, int FM, int FN, int EPI>
__global__ __launch_bounds__(256)
void gemm_nt(const u16* __restrict__ A, long Asb, int ldA,
             const u16* __restrict__ B, long Bsb, int ldB,
             void* __restrict__ Cout, long Csb, int ldC,
             float* __restrict__ red, int kspan)
{
  constexpr int NTH = WR * WC * 64;
  constexpr int WM = 16 * FM, WN = 16 * FN;
  constexpr int IA = BM * 8 / NTH;
  constexpr int IB = BN * 8 / NTH;
  static_assert(WR * WM == BM && WC * WN == BN && NTH == 256, "geometry");

  __shared__ unsigned char lds[(BM + BN) * 128];
  unsigned char* ldsA = lds;
  unsigned char* ldsB = lds + BM * 128;

  const int tid = threadIdx.x;
  const int b = blockIdx.z;
  const int n0 = blockIdx.x * BN;
  const int m0 = blockIdx.y * BM;

  const int wv = tid >> 6, lane = tid & 63;
  const int wr = wv / WC, wc = wv % WC;
  const int lan15 = lane & 15, l16 = lane >> 4;

  const u16* Ab = A + (size_t)b * Asb;
  const u16* Bb = B + (size_t)b * Bsb;

  f32x4 acc[FM][FN];
  #pragma unroll
  for (int i = 0; i < FM; ++i)
    #pragma unroll
    for (int j = 0; j < FN; ++j)
      #pragma unroll
      for (int e = 0; e < 4; ++e) acc[i][j][e] = 0.f;

  for (int k0 = 0; k0 < kspan; k0 += 64) {
    uint4 ra[IA], rb[IB];
    #pragma unroll
    for (int i = 0; i < IA; ++i) {
      int g = i * NTH + tid, r = g >> 3, cq = g & 7;
      ra[i] = *(const uint4*)(Ab + (size_t)(m0 + r) * ldA + k0 + cq * 8);
    }
    #pragma unroll
    for (int i = 0; i < IB; ++i) {
      int g = i * NTH + tid, r = g >> 3, cq = g & 7;
      rb[i] = *(const uint4*)(Bb + (size_t)(n0 + r) * ldB + k0 + cq * 8);
    }
    __syncthreads();
    #pragma unroll
    for (int i = 0; i < IA; ++i) {
      int g = i * NTH + tid, r = g >> 3, cq = g & 7;
      *(uint4*)(ldsA + r * 128 + ((cq ^ (r & 7)) << 4)) = ra[i];
    }
    #pragma unroll
    for (int i = 0; i < IB; ++i) {
      int g = i * NTH + tid, r = g >> 3, cq = g & 7;
      *(uint4*)(ldsB + r * 128 + ((cq ^ (r & 7)) << 4)) = rb[i];
    }
    __syncthreads();
    #pragma unroll
    for (int kk = 0; kk < 2; ++kk) {
      bf16x8 af[FM], bfr[FN];
      #pragma unroll
      for (int fm = 0; fm < FM; ++fm) {
        int row = wr * WM + fm * 16 + lan15;
        int ch = kk * 4 + l16;
        af[fm] = *(const bf16x8*)(ldsA + row * 128 + ((ch ^ (row & 7)) << 4));
      }
      #pragma unroll
      for (int fn = 0; fn < FN; ++fn) {
        int row = wc * WN + fn * 16 + lan15;
        int ch = kk * 4 + l16;
        bfr[fn] = *(const bf16x8*)(ldsB + row * 128 + ((ch ^ (row & 7)) << 4));
      }
      #pragma unroll
      for (int fm = 0; fm < FM; ++fm)
        #pragma unroll
        for (int fn = 0; fn < FN; ++fn)
          acc[fm][fn] = __builtin_amdgcn_mfma_f32_16x16x32_bf16(
              af[fm], bfr[fn], acc[fm][fn], 0, 0, 0);
    }
  }

  const int colbase = n0 + wc * WN;
  const int Mrows = BM * gridDim.y;

  if constexpr (EPI == 3) {
    u16* Cb = (u16*)Cout + (size_t)b * Csb;
    #pragma unroll
    for (int fm = 0; fm < FM; ++fm)
      #pragma unroll
      for (int r = 0; r < 4; ++r) {
        int m = m0 + wr * WM + fm * 16 + l16 * 4 + r;
        u16* crow = Cb + (size_t)m * ldC + colbase;
        #pragma unroll
        for (int fn = 0; fn < FN; ++fn)
          crow[fn * 16 + lan15] = f2b(fmaxf(acc[fm][fn][r], 0.f));
      }
  } else {  // EPI == 4
    float* Cb = (float*)Cout + (size_t)b * Csb;
    #pragma unroll
    for (int fm = 0; fm < FM; ++fm)
      #pragma unroll
      for (int r = 0; r < 4; ++r) {
        int m = m0 + wr * WM + fm * 16 + l16 * 4 + r;
        float* crow = Cb + (size_t)m * ldC + colbase;
        float s1 = 0.f, s2 = 0.f;
        #pragma unroll
        for (int fn = 0; fn < FN; ++fn) {
          float v = acc[fm][fn][r];
          s1 += v; s2 += v * v;
          crow[fn * 16 + lan15] = v;
        }
        s1 += __shfl_xor(s1, 1); s1 += __shfl_xor(s1, 2);
        s1 += __shfl_xor(s1, 4); s1 += __shfl_xor(s1, 8);
        s2 += __shfl_xor(s2, 1); s2 += __shfl_xor(s2, 2);
        s2 += __shfl_xor(s2, 4); s2 += __shfl_xor(s2, 8);
        if (lan15 == 0) {
          atomicAdd(red + ((size_t)b * Mrows + m) * 2 + 0, s1);
          atomicAdd(red + ((size_t)b * Mrows + m) * 2 + 1, s2);
        }
      }
  }
}

// convert w2 -> bf16
__global__ __launch_bounds__(256)
void convert_w2(const float* __restrict__ w2, u16* __restrict__ w2b)
{
  int i = blockIdx.x * 256 + threadIdx.x;   // float4 index, 16384 total
  float4 v = ((const float4*)w2)[i];
  ushort4 o;
  o.x = f2b(v.x); o.y = f2b(v.y); o.z = f2b(v.z); o.w = f2b(v.w);
  *(ushort4*)(w2b + (size_t)i * 4) = o;
}

__global__ __launch_bounds__(256)
void instnorm(float* __restrict__ out, const float* __restrict__ x,
              const float* __restrict__ sums)
{
  long i4 = (long)blockIdx.x * blockDim.x + threadIdx.x;
  constexpr long TOT = (long)BS * CH * NP / 4;
  if (i4 >= TOT) return;
  int bc = (int)(i4 / (NP / 4));
  float mean = sums[bc * 2 + 0] * (1.f / NP);
  float var  = sums[bc * 2 + 1] * (1.f / NP) - mean * mean;
  float is = rsqrtf(var + 1e-5f);
  float4 v = ((const float4*)out)[i4];
  float4 xv = ((const float4*)x)[i4];
  v.x = fmaxf((v.x - mean) * is + xv.x, 0.f);
  v.y = fmaxf((v.y - mean) * is + xv.y, 0.f);
  v.z = fmaxf((v.z - mean) * is + xv.z, 0.f);
  v.w = fmaxf((v.w - mean) * is + xv.w, 0.f);
  ((float4*)out)[i4] = v;
}

extern "C" void kernel_launch(void* const* d_in, const int* in_sizes, int n_in,
                              void* d_out, int out_size, void* d_ws, size_t ws_size,
                              hipStream_t stream)
{
  const float* x   = (const float*)d_in[0];
  const float* sw  = (const float*)d_in[1];
  const float* w1  = (const float*)d_in[2];
  const float* b1  = (const float*)d_in[3];
  const float* w2  = (const float*)d_in[4];
  const float* mu0 = (const float*)d_in[5];

  float* out  = (float*)d_out;                 // B*C*N fp32 (x2 staging -> out)
  float* mu_s = out + (size_t)BS * CH * NP;    // B*K*N fp32

  char* wsb = (char*)d_ws;
  float* xf    = (float*)(wsb);                  // B*C*N fp32 (dies after EM)
  u16*  xrT    = (u16*)(wsb);                    // aliases xf[0:134MB]
  u16*  mu_sT  = (u16*)(wsb + 134217728);        // aliases xf[134:167.5MB]
  float* mu_raw = (float*)(wsb + 268435456);     // B*K*N fp32
  float* Zp    = (float*)(wsb + 335544320);      // NSPLIT*B*K*C fp32
  float* zn    = (float*)(wsb + 352321536);      // B*K*C fp32
  u16*  zsmT   = (u16*)(wsb + 356515840);        // B*C*K bf16
  u16*  w2b    = (u16*)(wsb + 358612992);        // 256*256 bf16
  float* ss    = (float*)(wsb + 358744064);      // 3*B*K
  float* isums = (float*)(wsb + 358793216);      // B*C*2

  hipMemsetAsync(ss, 0, (size_t)(3 * BS * KB + 2 * BS * CH) * sizeof(float), stream);

  dim3 thr(256);

  convert_w2<<<dim3(64), thr, 0, stream>>>(w2, w2b);

  // conv1 (fp32): xf = W1 @ x + b1
  gemm_nn<128, 128, 32, 8, 8, 1><<<dim3(NP / 128, CH / 128, BS), thr, 0, stream>>>(
      w1, 0, x, (long)CH * NP, xf, (long)CH * NP, b1, nullptr, CH, NP, CH);

  const float* mu_in = mu0;
  long mu_sb = 0;
  const float* ssq = nullptr;
  for (int st = 0; st < 3; ++st) {
    zstep<<<dim3(CH / 64, NSPLIT, BS), thr, 0, stream>>>(mu_in, mu_sb, ssq, xf, Zp);
    em_softmax<<<dim3(BS), thr, 0, stream>>>(Zp, zn, zsmT, st == 2 ? 1 : 0);
    gemm_nn<64, 128, 32, 4, 8, 2><<<dim3(NP / 128, 1, BS), thr, 0, stream>>>(
        zn, (long)KB * CH, xf, (long)CH * NP, mu_raw, (long)KB * NP,
        nullptr, ss + (size_t)st * BS * KB, KB, NP, CH);
    mu_in = mu_raw; mu_sb = (long)KB * NP; ssq = ss + (size_t)st * BS * KB;
  }

  // mu_s (fp32 output) + mu_sT (bf16 [n][k]) — xf is dead now
  finalize_mu_t<<<dim3(NP / 64, BS), thr, 0, stream>>>(
      mu_raw, ss + (size_t)2 * BS * KB, sw, mu_s, mu_sT);

  // xrT[n][c] = relu(sum_k mu_sT[n][k] * zsmT[c][k])   (bf16 MFMA)
  gemm_nt<128, 128, 2, 2, 4, 4, 3><<<dim3(CH / 128, NP / 128, BS), thr, 0, stream>>>(
      mu_sT, (long)NP * KB, KB, zsmT, (long)CH * KB, KB,
      xrT, (long)NP * CH, CH, nullptr, KB);

  // conv2: x2[co][n] = sum_c w2[co][c] * xrT[n][c] (+ instnorm stats)
  gemm_nt<128, 128, 2, 2, 4, 4, 4><<<dim3(NP / 128, CH / 128, BS), thr, 0, stream>>>(
      w2b, 0, CH, xrT, (long)NP * CH, CH,
      out, (long)CH * NP, NP, isums, CH);

  instnorm<<<dim3(BS * CH * NP / 4 / 256), thr, 0, stream>>>(out, x, isums);
}

// Round 5
// 1217.271 us; speedup vs baseline: 1.7484x; 1.6011x over previous
//
#include <hip/hip_runtime.h>
#include <hip/hip_bf16.h>

typedef __bf16 bf16x8 __attribute__((ext_vector_type(8)));
typedef float  f32x4  __attribute__((ext_vector_type(4)));
typedef unsigned short u16;

constexpr int BS = 64;    // batch
constexpr int CH = 256;   // channels
constexpr int KB = 64;    // bases
constexpr int NP = 4096;  // pixels
constexpr int NSPLIT = 4; // z-step reduction split

__device__ inline u16 f2b(float f) {
  __hip_bfloat16 h = __float2bfloat16(f);
  return __builtin_bit_cast(u16, h);
}
__device__ inline float b2f(u16 u) { return __uint_as_float(((unsigned)u) << 16); }
__device__ inline void split2(float v, u16& h, u16& l) {
  h = f2b(v);
  l = f2b(v - b2f(h));
}

// ---------------------------------------------------------------------------
// Split-bf16 (3-MFMA) GEMM: C[m][n] = sum_k A[m][k]*B[..], ~fp32 accuracy.
// A: pre-split hi/lo bf16 planes, k-contiguous rows.
// B: fp32, split to hi/lo during staging.
//   BMODE 0 (NT): B[n][k] rows k-contiguous.
//   BMODE 1 (NN): B[k][n] reduction along rows -> transpose-staged in LDS.
// LDS per plane: row r, 128B = 64 bf16 of k; granule g (16B) holds k=8g..8g+7,
// XOR-swizzled: byte = r*128 + ((g ^ (r&7))<<4).
// EPI: 0 fp32 store w/ K-split plane offset (z-step)
//      1 +bias, fp32 store (conv1)
//      2 hi/lo store + rowwise sum-of-squares atomics (mu-step)
// ---------------------------------------------------------------------------
template<int BM, int BN, int WR, int WC, int FM, int FN, int BMODE, int EPI>
__global__ __launch_bounds__(256)
void gemm3(const u16* __restrict__ Ah, const u16* __restrict__ Al, long Asb, int ldA,
           const float* __restrict__ Bf, long Bsb, int ldB,
           void* __restrict__ C0, void* __restrict__ C1, long Csb, int ldC, long Cspl,
           const float* __restrict__ bias, float* __restrict__ red, int kspan)
{
  constexpr int WM = 16 * FM, WN = 16 * FN;
  static_assert(WR * WM == BM && WC * WN == BN && WR * WC == 4, "geometry");

  __shared__ unsigned char lds[(BM + BN) * 256];
  unsigned char* lAh = lds;
  unsigned char* lAl = lds + BM * 128;
  unsigned char* lBh = lds + BM * 256;
  unsigned char* lBl = lds + BM * 256 + BN * 128;

  const int tid = threadIdx.x, b = blockIdx.z;
  const int n0 = blockIdx.x * BN;
  const int m0 = (EPI == 0) ? 0 : blockIdx.y * BM;
  const int kbeg = (EPI == 0) ? blockIdx.y * kspan : 0;
  const int kend = kbeg + kspan;

  const int wv = tid >> 6, lane = tid & 63;
  const int wr = wv / WC, wc = wv % WC;
  const int lan15 = lane & 15, l16 = lane >> 4;

  const u16* Ahb = Ah + (size_t)b * Asb;
  const u16* Alb = Al + (size_t)b * Asb;
  const float* Bb = Bf + (size_t)b * Bsb;

  f32x4 acc[FM][FN];
  #pragma unroll
  for (int i = 0; i < FM; ++i)
    #pragma unroll
    for (int j = 0; j < FN; ++j)
      #pragma unroll
      for (int e = 0; e < 4; ++e) acc[i][j][e] = 0.f;

  for (int k0 = kbeg; k0 < kend; k0 += 64) {
    // ---- prefetch B globals into registers ----
    // BMODE 0 needs BN/16 float4s (2 per slot, BN*8/256 slots/thread);
    // BMODE 1 needs 8. (Round-4 bug: was BN/32 for BMODE 0 -> OOB stack.)
    float4 fb[BMODE ? 8 : (BN / 16)];
    if constexpr (BMODE == 0) {
      #pragma unroll
      for (int i = 0; i < BN * 8 / 256; ++i) {
        int s = tid + i * 256, r = s >> 3, g = s & 7;
        const float* src = Bb + (size_t)(n0 + r) * ldB + k0 + g * 8;
        fb[2 * i + 0] = *(const float4*)(src);
        fb[2 * i + 1] = *(const float4*)(src + 4);
      }
    } else {
      #pragma unroll
      for (int i = 0; i < BN / 64; ++i) {
        int mt = tid + i * 256;
        int kb = mt / (BN / 4), nb = mt % (BN / 4);
        #pragma unroll
        for (int rr = 0; rr < 4; ++rr)
          fb[i * 4 + rr] = *(const float4*)(Bb + (size_t)(k0 + kb * 4 + rr) * ldB + n0 + nb * 4);
      }
    }
    __syncthreads();   // previous iteration's LDS reads complete
    // ---- stage A (pre-split planes, direct) ----
    #pragma unroll
    for (int i = 0; i < BM * 8 / 256; ++i) {
      int s = tid + i * 256, r = s >> 3, g = s & 7;
      uint4 vh = *(const uint4*)(Ahb + (size_t)(m0 + r) * ldA + k0 + g * 8);
      uint4 vl = *(const uint4*)(Alb + (size_t)(m0 + r) * ldA + k0 + g * 8);
      int off = r * 128 + ((g ^ (r & 7)) << 4);
      *(uint4*)(lAh + off) = vh;
      *(uint4*)(lAl + off) = vl;
    }
    // ---- stage B (split fp32 -> hi/lo) ----
    if constexpr (BMODE == 0) {
      #pragma unroll
      for (int i = 0; i < BN * 8 / 256; ++i) {
        int s = tid + i * 256, r = s >> 3, g = s & 7;
        const float* v = (const float*)&fb[2 * i];
        u16 h[8], l[8];
        #pragma unroll
        for (int e = 0; e < 8; ++e) split2(v[e], h[e], l[e]);
        int off = r * 128 + ((g ^ (r & 7)) << 4);
        *(uint4*)(lBh + off) = *(uint4*)h;
        *(uint4*)(lBl + off) = *(uint4*)l;
      }
    } else {
      #pragma unroll
      for (int i = 0; i < BN / 64; ++i) {
        int mt = tid + i * 256;
        int kb = mt / (BN / 4), nb = mt % (BN / 4);
        #pragma unroll
        for (int j = 0; j < 4; ++j) {
          int nl = nb * 4 + j;
          ushort4 hv, lv;
          split2(((const float*)&fb[i * 4 + 0])[j], hv.x, lv.x);
          split2(((const float*)&fb[i * 4 + 1])[j], hv.y, lv.y);
          split2(((const float*)&fb[i * 4 + 2])[j], hv.z, lv.z);
          split2(((const float*)&fb[i * 4 + 3])[j], hv.w, lv.w);
          int off = nl * 128 + (((kb >> 1) ^ (nl & 7)) << 4) + ((kb & 1) << 3);
          *(ushort4*)(lBh + off) = hv;
          *(ushort4*)(lBl + off) = lv;
        }
      }
    }
    __syncthreads();
    // ---- compute: 3 MFMAs per fragment pair ----
    #pragma unroll
    for (int kk = 0; kk < 2; ++kk) {
      bf16x8 ah[FM], al[FM], bh[FN], bl[FN];
      #pragma unroll
      for (int fm = 0; fm < FM; ++fm) {
        int row = wr * WM + fm * 16 + lan15, ch = kk * 4 + l16;
        int off = row * 128 + ((ch ^ (row & 7)) << 4);
        ah[fm] = *(const bf16x8*)(lAh + off);
        al[fm] = *(const bf16x8*)(lAl + off);
      }
      #pragma unroll
      for (int fn = 0; fn < FN; ++fn) {
        int row = wc * WN + fn * 16 + lan15, ch = kk * 4 + l16;
        int off = row * 128 + ((ch ^ (row & 7)) << 4);
        bh[fn] = *(const bf16x8*)(lBh + off);
        bl[fn] = *(const bf16x8*)(lBl + off);
      }
      #pragma unroll
      for (int fm = 0; fm < FM; ++fm)
        #pragma unroll
        for (int fn = 0; fn < FN; ++fn) {
          acc[fm][fn] = __builtin_amdgcn_mfma_f32_16x16x32_bf16(ah[fm], bh[fn], acc[fm][fn], 0, 0, 0);
          acc[fm][fn] = __builtin_amdgcn_mfma_f32_16x16x32_bf16(ah[fm], bl[fn], acc[fm][fn], 0, 0, 0);
          acc[fm][fn] = __builtin_amdgcn_mfma_f32_16x16x32_bf16(al[fm], bh[fn], acc[fm][fn], 0, 0, 0);
        }
    }
  }

  const int colbase = n0 + wc * WN;

  if constexpr (EPI == 0) {
    float* Cb = (float*)C0 + (size_t)blockIdx.y * Cspl + (size_t)b * Csb;
    #pragma unroll
    for (int fm = 0; fm < FM; ++fm)
      #pragma unroll
      for (int r = 0; r < 4; ++r) {
        int m = m0 + wr * WM + fm * 16 + l16 * 4 + r;
        float* crow = Cb + (size_t)m * ldC + colbase;
        #pragma unroll
        for (int fn = 0; fn < FN; ++fn) crow[fn * 16 + lan15] = acc[fm][fn][r];
      }
  } else if constexpr (EPI == 1) {
    float* Cb = (float*)C0 + (size_t)b * Csb;
    #pragma unroll
    for (int fm = 0; fm < FM; ++fm)
      #pragma unroll
      for (int r = 0; r < 4; ++r) {
        int m = m0 + wr * WM + fm * 16 + l16 * 4 + r;
        float bv = bias[m];
        float* crow = Cb + (size_t)m * ldC + colbase;
        #pragma unroll
        for (int fn = 0; fn < FN; ++fn) crow[fn * 16 + lan15] = acc[fm][fn][r] + bv;
      }
  } else {  // EPI == 2: hi/lo store + row ssq
    u16* Ch = (u16*)C0 + (size_t)b * Csb;
    u16* Cl = (u16*)C1 + (size_t)b * Csb;
    #pragma unroll
    for (int fm = 0; fm < FM; ++fm)
      #pragma unroll
      for (int r = 0; r < 4; ++r) {
        int m = m0 + wr * WM + fm * 16 + l16 * 4 + r;
        float s = 0.f;
        #pragma unroll
        for (int fn = 0; fn < FN; ++fn) {
          float v = acc[fm][fn][r];
          s += v * v;
          u16 h, l;
          split2(v, h, l);
          Ch[(size_t)m * ldC + colbase + fn * 16 + lan15] = h;
          Cl[(size_t)m * ldC + colbase + fn * 16 + lan15] = l;
        }
        s += __shfl_xor(s, 1); s += __shfl_xor(s, 2);
        s += __shfl_xor(s, 4); s += __shfl_xor(s, 8);
        if (lan15 == 0) atomicAdd(red + (size_t)b * BM + m, s);
      }
  }
}

// ---------------------------------------------------------------------------
// softmax over K + channel normalize; logits scaled by fused mu-l2norm rsk.
// Outputs zn hi/lo planes [k][c] and per-(b,k) channel-sum denom csum.
// ---------------------------------------------------------------------------
__global__ __launch_bounds__(256)
void em_softmax(const float* __restrict__ Zp, const float* __restrict__ ssq,
                u16* __restrict__ znh, u16* __restrict__ znl,
                float* __restrict__ csum)
{
  __shared__ float rsk[KB];
  __shared__ float wsum[4 * KB];
  __shared__ float rsc[KB];
  const int b = blockIdx.x, t = threadIdx.x;
  const int lane = t & 63, w = t >> 6;
  constexpr long SPOFF = (long)BS * KB * CH;

  if (t < KB) rsk[t] = ssq ? 1.f / (1e-6f + sqrtf(ssq[b * KB + t])) : 1.f;
  __syncthreads();

  float z[KB];
  #pragma unroll
  for (int k = 0; k < KB; ++k) {
    long base = ((long)b * KB + k) * CH + t;
    z[k] = (Zp[base] + Zp[SPOFF + base] + Zp[2 * SPOFF + base] +
            Zp[3 * SPOFF + base]) * rsk[k];
  }
  float m = z[0];
  #pragma unroll
  for (int k = 1; k < KB; ++k) m = fmaxf(m, z[k]);
  float s = 0.f;
  #pragma unroll
  for (int k = 0; k < KB; ++k) { z[k] = expf(z[k] - m); s += z[k]; }
  float inv = 1.f / s;
  #pragma unroll
  for (int k = 0; k < KB; ++k) z[k] *= inv;

  #pragma unroll
  for (int k = 0; k < KB; ++k) {
    float v = z[k];
    #pragma unroll
    for (int o = 32; o >= 1; o >>= 1) v += __shfl_xor(v, o);
    if (lane == 0) wsum[w * KB + k] = v;
  }
  __syncthreads();
  if (t < KB) {
    float v = wsum[t] + wsum[KB + t] + wsum[2 * KB + t] + wsum[3 * KB + t];
    float d = 1e-6f + v;
    rsc[t] = 1.f / d;
    csum[b * KB + t] = d;
  }
  __syncthreads();

  #pragma unroll
  for (int k = 0; k < KB; ++k) {
    float v = z[k] * rsc[k];
    u16 h, l;
    split2(v, h, l);
    long o = ((long)b * KB + k) * CH + t;
    znh[o] = h;
    znl[o] = l;
  }
}

// ---------------------------------------------------------------------------
// Rebuild raw softmax transposed: zsmT[b][c][k] = bf16(zn[b][k][c] * csum[b][k])
// (runs after the last em_softmax; zsmT may alias dead Zp — kernel-boundary safe)
// ---------------------------------------------------------------------------
__global__ __launch_bounds__(256)
void zsm_build(const u16* __restrict__ znh, const u16* __restrict__ znl,
               const float* __restrict__ csum, u16* __restrict__ zsmT)
{
  __shared__ u16 ldsT[64][72];
  const int tid = threadIdx.x;
  const int b = blockIdx.y, c0 = blockIdx.x * 64;
  #pragma unroll
  for (int i = 0; i < 2; ++i) {
    int slot = tid + i * 256;   // 512 slots = 64 k x 8 c-octets
    int k = slot >> 3, cq = slot & 7;
    size_t base = ((size_t)b * KB + k) * CH + c0 + cq * 8;
    uint4 vh = *(const uint4*)(znh + base);
    uint4 vl = *(const uint4*)(znl + base);
    float sc = csum[b * KB + k];
    unsigned hh[4] = {vh.x, vh.y, vh.z, vh.w};
    unsigned ll[4] = {vl.x, vl.y, vl.z, vl.w};
    #pragma unroll
    for (int j = 0; j < 4; ++j) {
      float f0 = (b2f((u16)(hh[j] & 0xffff)) + b2f((u16)(ll[j] & 0xffff))) * sc;
      float f1 = (b2f((u16)(hh[j] >> 16))    + b2f((u16)(ll[j] >> 16)))    * sc;
      ldsT[cq * 8 + 2 * j + 0][k] = f2b(f0);
      ldsT[cq * 8 + 2 * j + 1][k] = f2b(f1);
    }
  }
  __syncthreads();
  #pragma unroll
  for (int i = 0; i < 2; ++i) {
    int slot = tid + i * 256;
    int c = slot >> 3, kq = slot & 7;
    uint4 v = *(const uint4*)(&ldsT[c][kq * 8]);
    *(uint4*)(zsmT + ((size_t)b * CH + c0 + c) * KB + kq * 8) = v;
  }
}

// finalize: mu_s fp32 output (hi+lo reconstructed, scaled) + mu_sT bf16 [n][k]
__global__ __launch_bounds__(256)
void finalize_mu_t(const u16* __restrict__ muh, const u16* __restrict__ mul,
                   const float* __restrict__ ssq, const float* __restrict__ sw,
                   float* __restrict__ mu_s, u16* __restrict__ mu_sT)
{
  __shared__ u16 ldsT[64][72];
  const int tid = threadIdx.x;
  const int b = blockIdx.y, n0 = blockIdx.x * 64;

  #pragma unroll
  for (int i = 0; i < 2; ++i) {
    int slot = tid + i * 256;      // 512 slots: 64 k x 8 n-octets
    int k = slot >> 3, nq = slot & 7;
    float sc = sw[b * KB + k] / (1e-6f + sqrtf(ssq[b * KB + k]));
    size_t base = ((size_t)b * KB + k) * NP + n0 + nq * 8;
    uint4 vh = *(const uint4*)(muh + base);
    uint4 vl = *(const uint4*)(mul + base);
    unsigned hh[4] = {vh.x, vh.y, vh.z, vh.w};
    unsigned ll[4] = {vl.x, vl.y, vl.z, vl.w};
    float f[8];
    #pragma unroll
    for (int j = 0; j < 4; ++j) {
      f[2 * j + 0] = (b2f((u16)(hh[j] & 0xffff)) + b2f((u16)(ll[j] & 0xffff))) * sc;
      f[2 * j + 1] = (b2f((u16)(hh[j] >> 16))    + b2f((u16)(ll[j] >> 16)))    * sc;
    }
    float4 lo = {f[0], f[1], f[2], f[3]}, hi = {f[4], f[5], f[6], f[7]};
    *(float4*)(mu_s + base) = lo;
    *(float4*)(mu_s + base + 4) = hi;
    #pragma unroll
    for (int j = 0; j < 8; ++j) ldsT[nq * 8 + j][k] = f2b(f[j]);
  }
  __syncthreads();
  #pragma unroll
  for (int i = 0; i < 2; ++i) {
    int slot = tid + i * 256;
    int n = slot >> 3, kq = slot & 7;
    uint4 v = *(const uint4*)(&ldsT[n][kq * 8]);
    *(uint4*)(mu_sT + (size_t)b * NP * KB + (size_t)(n0 + n) * KB + kq * 8) = v;
  }
}

// ---------------------------------------------------------------------------
// Pure-bf16 MFMA NT GEMM (round-3 proven): C[m][n] = sum_k A[m][k]*B[n][k].
// EPI: 3 relu + bf16 store (xrT), 4 fp32 store + row sum/sumsq (conv2).
// ---------------------------------------------------------------------------
template<int BM, int BN, int WR, int WC, int FM, int FN, int EPI>
__global__ __launch_bounds__(256)
void gemm_nt(const u16* __restrict__ A, long Asb, int ldA,
             const u16* __restrict__ B, long Bsb, int ldB,
             void* __restrict__ Cout, long Csb, int ldC,
             float* __restrict__ red, int kspan)
{
  constexpr int NTH = WR * WC * 64;
  constexpr int WM = 16 * FM, WN = 16 * FN;
  constexpr int IA = BM * 8 / NTH;
  constexpr int IB = BN * 8 / NTH;
  static_assert(WR * WM == BM && WC * WN == BN && NTH == 256, "geometry");

  __shared__ unsigned char lds[(BM + BN) * 128];
  unsigned char* ldsA = lds;
  unsigned char* ldsB = lds + BM * 128;

  const int tid = threadIdx.x;
  const int b = blockIdx.z;
  const int n0 = blockIdx.x * BN;
  const int m0 = blockIdx.y * BM;

  const int wv = tid >> 6, lane = tid & 63;
  const int wr = wv / WC, wc = wv % WC;
  const int lan15 = lane & 15, l16 = lane >> 4;

  const u16* Ab = A + (size_t)b * Asb;
  const u16* Bb = B + (size_t)b * Bsb;

  f32x4 acc[FM][FN];
  #pragma unroll
  for (int i = 0; i < FM; ++i)
    #pragma unroll
    for (int j = 0; j < FN; ++j)
      #pragma unroll
      for (int e = 0; e < 4; ++e) acc[i][j][e] = 0.f;

  for (int k0 = 0; k0 < kspan; k0 += 64) {
    uint4 ra[IA], rb[IB];
    #pragma unroll
    for (int i = 0; i < IA; ++i) {
      int g = i * NTH + tid, r = g >> 3, cq = g & 7;
      ra[i] = *(const uint4*)(Ab + (size_t)(m0 + r) * ldA + k0 + cq * 8);
    }
    #pragma unroll
    for (int i = 0; i < IB; ++i) {
      int g = i * NTH + tid, r = g >> 3, cq = g & 7;
      rb[i] = *(const uint4*)(Bb + (size_t)(n0 + r) * ldB + k0 + cq * 8);
    }
    __syncthreads();
    #pragma unroll
    for (int i = 0; i < IA; ++i) {
      int g = i * NTH + tid, r = g >> 3, cq = g & 7;
      *(uint4*)(ldsA + r * 128 + ((cq ^ (r & 7)) << 4)) = ra[i];
    }
    #pragma unroll
    for (int i = 0; i < IB; ++i) {
      int g = i * NTH + tid, r = g >> 3, cq = g & 7;
      *(uint4*)(ldsB + r * 128 + ((cq ^ (r & 7)) << 4)) = rb[i];
    }
    __syncthreads();
    #pragma unroll
    for (int kk = 0; kk < 2; ++kk) {
      bf16x8 af[FM], bfr[FN];
      #pragma unroll
      for (int fm = 0; fm < FM; ++fm) {
        int row = wr * WM + fm * 16 + lan15;
        int ch = kk * 4 + l16;
        af[fm] = *(const bf16x8*)(ldsA + row * 128 + ((ch ^ (row & 7)) << 4));
      }
      #pragma unroll
      for (int fn = 0; fn < FN; ++fn) {
        int row = wc * WN + fn * 16 + lan15;
        int ch = kk * 4 + l16;
        bfr[fn] = *(const bf16x8*)(ldsB + row * 128 + ((ch ^ (row & 7)) << 4));
      }
      #pragma unroll
      for (int fm = 0; fm < FM; ++fm)
        #pragma unroll
        for (int fn = 0; fn < FN; ++fn)
          acc[fm][fn] = __builtin_amdgcn_mfma_f32_16x16x32_bf16(
              af[fm], bfr[fn], acc[fm][fn], 0, 0, 0);
    }
  }

  const int colbase = n0 + wc * WN;
  const int Mrows = BM * gridDim.y;

  if constexpr (EPI == 3) {
    u16* Cb = (u16*)Cout + (size_t)b * Csb;
    #pragma unroll
    for (int fm = 0; fm < FM; ++fm)
      #pragma unroll
      for (int r = 0; r < 4; ++r) {
        int m = m0 + wr * WM + fm * 16 + l16 * 4 + r;
        u16* crow = Cb + (size_t)m * ldC + colbase;
        #pragma unroll
        for (int fn = 0; fn < FN; ++fn)
          crow[fn * 16 + lan15] = f2b(fmaxf(acc[fm][fn][r], 0.f));
      }
  } else {  // EPI == 4
    float* Cb = (float*)Cout + (size_t)b * Csb;
    #pragma unroll
    for (int fm = 0; fm < FM; ++fm)
      #pragma unroll
      for (int r = 0; r < 4; ++r) {
        int m = m0 + wr * WM + fm * 16 + l16 * 4 + r;
        float* crow = Cb + (size_t)m * ldC + colbase;
        float s1 = 0.f, s2 = 0.f;
        #pragma unroll
        for (int fn = 0; fn < FN; ++fn) {
          float v = acc[fm][fn][r];
          s1 += v; s2 += v * v;
          crow[fn * 16 + lan15] = v;
        }
        s1 += __shfl_xor(s1, 1); s1 += __shfl_xor(s1, 2);
        s1 += __shfl_xor(s1, 4); s1 += __shfl_xor(s1, 8);
        s2 += __shfl_xor(s2, 1); s2 += __shfl_xor(s2, 2);
        s2 += __shfl_xor(s2, 4); s2 += __shfl_xor(s2, 8);
        if (lan15 == 0) {
          atomicAdd(red + ((size_t)b * Mrows + m) * 2 + 0, s1);
          atomicAdd(red + ((size_t)b * Mrows + m) * 2 + 1, s2);
        }
      }
  }
}

// convert inputs: w1 -> hi/lo, w2 -> bf16, mu0 -> hi/lo
__global__ __launch_bounds__(256)
void convert_in(const float* __restrict__ w1, const float* __restrict__ w2,
                const float* __restrict__ mu0,
                u16* __restrict__ w1h, u16* __restrict__ w1l,
                u16* __restrict__ w2b,
                u16* __restrict__ mu0h, u16* __restrict__ mu0l)
{
  int i = blockIdx.x * 256 + threadIdx.x;   // float4 slot, 98304 total
  if (i < 16384) {
    float4 v = ((const float4*)w1)[i];
    ushort4 h, l;
    split2(v.x, h.x, l.x); split2(v.y, h.y, l.y);
    split2(v.z, h.z, l.z); split2(v.w, h.w, l.w);
    *(ushort4*)(w1h + (size_t)i * 4) = h;
    *(ushort4*)(w1l + (size_t)i * 4) = l;
  } else if (i < 32768) {
    int j = i - 16384;
    float4 v = ((const float4*)w2)[j];
    ushort4 o = { f2b(v.x), f2b(v.y), f2b(v.z), f2b(v.w) };
    *(ushort4*)(w2b + (size_t)j * 4) = o;
  } else {
    int j = i - 32768;
    float4 v = ((const float4*)mu0)[j];
    ushort4 h, l;
    split2(v.x, h.x, l.x); split2(v.y, h.y, l.y);
    split2(v.z, h.z, l.z); split2(v.w, h.w, l.w);
    *(ushort4*)(mu0h + (size_t)j * 4) = h;
    *(ushort4*)(mu0l + (size_t)j * 4) = l;
  }
}

__global__ __launch_bounds__(256)
void instnorm(float* __restrict__ out, const float* __restrict__ x,
              const float* __restrict__ sums)
{
  long i4 = (long)blockIdx.x * blockDim.x + threadIdx.x;
  constexpr long TOT = (long)BS * CH * NP / 4;
  if (i4 >= TOT) return;
  int bc = (int)(i4 / (NP / 4));
  float mean = sums[bc * 2 + 0] * (1.f / NP);
  float var  = sums[bc * 2 + 1] * (1.f / NP) - mean * mean;
  float is = rsqrtf(var + 1e-5f);
  float4 v = ((const float4*)out)[i4];
  float4 xv = ((const float4*)x)[i4];
  v.x = fmaxf((v.x - mean) * is + xv.x, 0.f);
  v.y = fmaxf((v.y - mean) * is + xv.y, 0.f);
  v.z = fmaxf((v.z - mean) * is + xv.z, 0.f);
  v.w = fmaxf((v.w - mean) * is + xv.w, 0.f);
  ((float4*)out)[i4] = v;
}

extern "C" void kernel_launch(void* const* d_in, const int* in_sizes, int n_in,
                              void* d_out, int out_size, void* d_ws, size_t ws_size,
                              hipStream_t stream)
{
  const float* x   = (const float*)d_in[0];
  const float* sw  = (const float*)d_in[1];
  const float* w1  = (const float*)d_in[2];
  const float* b1  = (const float*)d_in[3];
  const float* w2  = (const float*)d_in[4];
  const float* mu0 = (const float*)d_in[5];

  float* out  = (float*)d_out;                 // B*C*N fp32 (x2 staging -> out)
  float* mu_s = out + (size_t)BS * CH * NP;    // B*K*N fp32

  // ws layout — high water 358,154,240 B (< 358,924,288 proven in round 3)
  char* wsb = (char*)d_ws;
  float* xf    = (float*)(wsb);                  // 256MB fp32 (dead after last mu-step)
  u16*  xrT    = (u16*)(wsb);                    // aliases xf[0:134MB]
  u16*  mu_sT  = (u16*)(wsb + 134217728);        // aliases xf[134:167.5MB]
  u16*  muh    = (u16*)(wsb + 268435456);        // B*K*N bf16 hi (33.5MB)
  u16*  mul    = (u16*)(wsb + 301989888);        // B*K*N bf16 lo (33.5MB)
  float* Zp    = (float*)(wsb + 335544320);      // NSPLIT*B*K*C fp32 (16.8MB)
  u16*  zsmT   = (u16*)(wsb + 335544320);        // aliases Zp (built after Zp dead)
  u16*  znh    = (u16*)(wsb + 352321536);        // B*K*C bf16 hi (2MB)
  u16*  znl    = (u16*)(wsb + 354418688);        // B*K*C bf16 lo (2MB)
  u16*  w1h    = (u16*)(wsb + 356515840);
  u16*  w1l    = (u16*)(wsb + 356646912);
  u16*  w2b    = (u16*)(wsb + 356777984);
  u16*  mu0h   = (u16*)(wsb + 356909056);
  u16*  mu0l   = (u16*)(wsb + 357433344);
  float* csum  = (float*)(wsb + 357957632);      // B*K fp32 (16KB)
  float* ss    = (float*)(wsb + 357974016);      // 3*B*K (48KB)
  float* isums = (float*)(wsb + 358023168);      // B*C*2 (128KB)

  hipMemsetAsync(ss, 0, (size_t)(3 * BS * KB + 2 * BS * CH) * sizeof(float), stream);

  dim3 thr(256);

  convert_in<<<dim3(384), thr, 0, stream>>>(w1, w2, mu0, w1h, w1l, w2b, mu0h, mu0l);

  // conv1 (split-bf16): xf[co][n] = sum_ci w1[co][ci] * x[ci][n] + b1
  gemm3<128, 128, 2, 2, 4, 4, 1, 1><<<dim3(NP / 128, CH / 128, BS), thr, 0, stream>>>(
      w1h, w1l, 0, CH, x, (long)CH * NP, NP,
      xf, nullptr, (long)CH * NP, NP, 0, b1, nullptr, CH);

  const u16* muh_in = mu0h;
  const u16* mul_in = mu0l;
  long mu_sb = 0;
  const float* ssq = nullptr;
  for (int st = 0; st < 3; ++st) {
    // z-step: Zp[sp][b][k][c] = sum_{n in sp} mu[k][n] * xf[c][n]
    gemm3<64, 128, 2, 2, 2, 4, 0, 0><<<dim3(CH / 128, NSPLIT, BS), thr, 0, stream>>>(
        muh_in, mul_in, mu_sb, NP, xf, (long)CH * NP, NP,
        Zp, nullptr, (long)KB * CH, CH, (long)BS * KB * CH, nullptr, nullptr,
        NP / NSPLIT);
    // softmax over K + channel normalize (fused mu l2norm on logits)
    em_softmax<<<dim3(BS), thr, 0, stream>>>(Zp, ssq, znh, znl, csum);
    // mu-step: mu[k][n] = sum_c zn[k][c] * xf[c][n]  (+ row ssq)
    gemm3<64, 128, 2, 2, 2, 4, 1, 2><<<dim3(NP / 128, 1, BS), thr, 0, stream>>>(
        znh, znl, (long)KB * CH, CH, xf, (long)CH * NP, NP,
        muh, mul, (long)KB * NP, NP, 0, nullptr, ss + (size_t)st * BS * KB, CH);
    muh_in = muh; mul_in = mul; mu_sb = (long)KB * NP;
    ssq = ss + (size_t)st * BS * KB;
  }

  // zsmT[b][c][k] = bf16(zn * csum)  (Zp dead; zsmT aliases it safely)
  zsm_build<<<dim3(CH / 64, BS), thr, 0, stream>>>(znh, znl, csum, zsmT);

  // mu_s (fp32 output) + mu_sT (bf16 [n][k]) — xf is dead now
  finalize_mu_t<<<dim3(NP / 64, BS), thr, 0, stream>>>(
      muh, mul, ss + (size_t)2 * BS * KB, sw, mu_s, mu_sT);

  // xrT[n][c] = relu(sum_k mu_sT[n][k] * zsmT[c][k])   (bf16 MFMA, proven)
  gemm_nt<128, 128, 2, 2, 4, 4, 3><<<dim3(CH / 128, NP / 128, BS), thr, 0, stream>>>(
      mu_sT, (long)NP * KB, KB, zsmT, (long)CH * KB, KB,
      xrT, (long)NP * CH, CH, nullptr, KB);

  // conv2: x2[co][n] = sum_c w2[co][c] * xrT[n][c] (+ instnorm stats)
  gemm_nt<128, 128, 2, 2, 4, 4, 4><<<dim3(NP / 128, CH / 128, BS), thr, 0, stream>>>(
      w2b, 0, CH, xrT, (long)NP * CH, CH,
      out, (long)CH * NP, NP, isums, CH);

  instnorm<<<dim3(BS * CH * NP / 4 / 256), thr, 0, stream>>>(out, x, isums);
}